// Round 1
// baseline (1105.322 us; speedup 1.0000x reference)
//
#include <hip/hip_runtime.h>

// ActionDetokenizer: out[b,j,k] = sum_d x[b, j+1, d] * W[j,d,k] + bias[j,k]
// x: (B, 13, 256) f32, W: (12, 256, 2) f32, bias: (12, 2) f32, out: (B, 12, 2) f32
// Strategy: one wave per (b,j) pair, grid-stride. Lane l loads float4 of x
// (d = 4l) -> 1KB coalesced per pair; W block (8 floats/lane) is L1-resident.
// Butterfly shfl_xor reduction, lane 0 stores float2. Memory-bound (~812 MB).

#define WAVE 64

__global__ __launch_bounds__(256) void detok_kernel(
    const float* __restrict__ x, const float* __restrict__ W,
    const float* __restrict__ bias, float* __restrict__ out,
    int total_pairs)
{
    const int lane = (int)(threadIdx.x & 63u);
    const int waves_per_block = (int)(blockDim.x >> 6);
    const int wave_in_block = (int)(threadIdx.x >> 6);
    int wave_id = (int)blockIdx.x * waves_per_block + wave_in_block;
    const int num_waves = (int)gridDim.x * waves_per_block;

    for (int p = wave_id; p < total_pairs; p += num_waves) {
        const int b = p / 12;
        const int j = p - b * 12;

        // x row for (b, node j+1), lane's float4 slice
        const float4* xp =
            (const float4*)(x + ((size_t)(b * 13 + j + 1)) * 256) + lane;
        const float4 xv = *xp;

        // W[j, d=4l..4l+3, k=0..1]: 8 consecutive floats at j*512 + 8l
        const float4* wp = (const float4*)(W + (size_t)j * 512 + (size_t)lane * 8);
        const float4 w0 = wp[0];  // (d0k0, d0k1, d1k0, d1k1)
        const float4 w1 = wp[1];  // (d2k0, d2k1, d3k0, d3k1)

        float s0 = xv.x * w0.x + xv.y * w0.z + xv.z * w1.x + xv.w * w1.z;
        float s1 = xv.x * w0.y + xv.y * w0.w + xv.z * w1.y + xv.w * w1.w;

        // full-wave butterfly reduction (64 lanes)
        #pragma unroll
        for (int off = 32; off > 0; off >>= 1) {
            s0 += __shfl_xor(s0, off, WAVE);
            s1 += __shfl_xor(s1, off, WAVE);
        }

        if (lane == 0) {
            float2 r;
            r.x = s0 + bias[j * 2 + 0];
            r.y = s1 + bias[j * 2 + 1];
            *(float2*)(out + (size_t)p * 2) = r;
        }
    }
}

extern "C" void kernel_launch(void* const* d_in, const int* in_sizes, int n_in,
                              void* d_out, int out_size, void* d_ws, size_t ws_size,
                              hipStream_t stream) {
    const float* x    = (const float*)d_in[0];
    const float* W    = (const float*)d_in[1];
    const float* bias = (const float*)d_in[2];
    float* out        = (float*)d_out;

    const int B = in_sizes[0] / (13 * 256);
    const int total_pairs = B * 12;

    // 4096 blocks x 256 threads = 16384 waves; each wave loops ~48 pairs.
    const int blocks = 4096;
    detok_kernel<<<blocks, 256, 0, stream>>>(x, W, bias, out, total_pairs);
}

// Round 2
// 1094.025 us; speedup vs baseline: 1.0103x; 1.0103x over previous
//
#include <hip/hip_runtime.h>

// ActionDetokenizer: out[b,j,k] = sum_d x[b, j+1, d] * W[j,d,k] + bias[j,k]
// x: (B,13,256) f32, W: (12,256,2) f32, bias: (12,2) f32, out: (B,12,2) f32.
//
// R1 redesign: 4-lane-group reduction instead of 64-lane butterfly.
//   wave batch = 16 pairs; group g = lane>>2 owns pair p0+g; q = lane&3 owns
//   d in {4q..4q+3} + 16*i, i=0..15.  Per batch: 48 independent float4 loads
//   (high MLP), 128 FMA/lane, then ONLY 4 cross-lane ops (xor1+xor2 swizzles)
//   for all 16 pairs (was 12 per pair).  Coalesced float2 store burst.
// Memory-bound target: ~812 MB -> ~130 us at 6.3 TB/s.

__global__ __launch_bounds__(256) void detok_kernel(
    const float* __restrict__ x, const float* __restrict__ W,
    const float* __restrict__ bias, float* __restrict__ out,
    int num_batches)
{
    const int lane = (int)(threadIdx.x & 63u);
    const int g = lane >> 2;   // 0..15: pair within batch
    const int q = lane & 3;    // 0..3 : d-slice owner

    const int wave_id = (int)blockIdx.x * ((int)blockDim.x >> 6) + ((int)threadIdx.x >> 6);
    const int num_waves = (int)gridDim.x * ((int)blockDim.x >> 6);

    for (int batch = wave_id; batch < num_batches; batch += num_waves) {
        const int p = (batch << 4) + g;
        const int b = p / 12;
        const int j = p - b * 12;

        // lane's x slice: d = 16*i + 4*q, i = 0..15
        const float* xrow = x + (size_t)(b * 13 + j + 1) * 256 + q * 4;
        // lane's W slice: floats at j*512 + 32*i + 8*q (+0..7), 32B-aligned
        const float* wrow = W + (size_t)j * 512 + q * 8;

        float s0 = 0.f, s1 = 0.f;
        #pragma unroll
        for (int i = 0; i < 16; ++i) {
            const float4 xv = *(const float4*)(xrow + i * 16);
            const float4 w0 = *(const float4*)(wrow + i * 32);      // d0k0 d0k1 d1k0 d1k1
            const float4 w1 = *(const float4*)(wrow + i * 32 + 4);  // d2k0 d2k1 d3k0 d3k1
            s0 += xv.x * w0.x + xv.y * w0.z + xv.z * w1.x + xv.w * w1.z;
            s1 += xv.x * w0.y + xv.y * w0.w + xv.z * w1.y + xv.w * w1.w;
        }

        // reduce across the 4 q-lanes only (cheap ds_swizzle patterns)
        s0 += __shfl_xor(s0, 1, 64);
        s1 += __shfl_xor(s1, 1, 64);
        s0 += __shfl_xor(s0, 2, 64);
        s1 += __shfl_xor(s1, 2, 64);

        if (q == 0) {
            float2 r;
            r.x = s0 + bias[j * 2 + 0];
            r.y = s1 + bias[j * 2 + 1];
            *(float2*)(out + (size_t)p * 2) = r;   // 16 lanes, consecutive 8B: coalesced
        }
    }
}

extern "C" void kernel_launch(void* const* d_in, const int* in_sizes, int n_in,
                              void* d_out, int out_size, void* d_ws, size_t ws_size,
                              hipStream_t stream) {
    const float* x    = (const float*)d_in[0];
    const float* W    = (const float*)d_in[1];
    const float* bias = (const float*)d_in[2];
    float* out        = (float*)d_out;

    const int B = in_sizes[0] / (13 * 256);
    const int total_pairs = B * 12;          // 786432, divisible by 16
    const int num_batches = total_pairs >> 4; // 49152

    // 12288 blocks x 4 waves = 49152 waves -> one batch per wave (grid-stride
    // loop kept for generality).
    const int blocks = 12288;
    detok_kernel<<<blocks, 256, 0, stream>>>(x, W, bias, out, num_batches);
}

// Round 3
// 1082.548 us; speedup vs baseline: 1.0210x; 1.0106x over previous
//
#include <hip/hip_runtime.h>

// ActionDetokenizer: out[b,j,k] = sum_d x[b, j+1, d] * W[j,d,k] + bias[j,k]
// x: (B,13,256) f32, W: (12,256,2) f32, bias: (12,2) f32, out: (B,12,2) f32.
//
// R3: 4-lane group handles FOUR pairs sharing the same joint j:
//   p, p+192, p+384, p+576  (192 == 0 mod 12 -> same j, b advances by 16).
//   W fragment loaded once, reused x4 (VMEM insts: 6 loads / 4 KB useful vs
//   12 in R2). 16 independent x-loads in flight per i-window -> high MLP.
//   Reduction: xor1+xor2 over the 4 q-lanes, 4 shfl per pair amortized.
// Memory-bound target: ~812 MB of x -> ~130 us at 6.3 TB/s.

__global__ __launch_bounds__(256) void detok_kernel(
    const float* __restrict__ x, const float* __restrict__ W,
    const float* __restrict__ bias, float* __restrict__ out,
    int num_quads)
{
    const int lane = (int)(threadIdx.x & 63u);
    const int g = lane >> 2;   // 0..15: pair-group within wave
    const int q = lane & 3;    // 0..3 : d-slice owner

    const int wave_id = (int)blockIdx.x * ((int)blockDim.x >> 6) + ((int)threadIdx.x >> 6);
    const int num_waves = (int)gridDim.x * ((int)blockDim.x >> 6);

    const size_t row_stride = 13 * 256;   // floats per b in x

    for (int wq = wave_id; wq < num_quads; wq += num_waves) {
        // enumerate batch base = m*48 + r so that {base, base+12, base+24,
        // base+36} give pairs p + 192k (same j, b + 16k)
        const int m = wq / 12;
        const int r = wq - m * 12;
        const int base = m * 48 + r;
        const int p = (base << 4) + g;
        const int b = p / 12;
        const int j = p - b * 12;

        const float* wrow = W + (size_t)j * 512 + q * 8;
        const float* x0 = x + (size_t)(b * 13 + j + 1) * 256 + q * 4;
        const float* x1 = x0 + 16 * row_stride;
        const float* x2 = x0 + 32 * row_stride;
        const float* x3 = x0 + 48 * row_stride;

        float a00 = 0.f, a01 = 0.f, a10 = 0.f, a11 = 0.f;
        float a20 = 0.f, a21 = 0.f, a30 = 0.f, a31 = 0.f;

        #pragma unroll
        for (int i = 0; i < 16; ++i) {
            const float4 w0 = *(const float4*)(wrow + i * 32);      // d0k0 d0k1 d1k0 d1k1
            const float4 w1 = *(const float4*)(wrow + i * 32 + 4);  // d2k0 d2k1 d3k0 d3k1
            const float4 v0 = *(const float4*)(x0 + i * 16);
            const float4 v1 = *(const float4*)(x1 + i * 16);
            const float4 v2 = *(const float4*)(x2 + i * 16);
            const float4 v3 = *(const float4*)(x3 + i * 16);
            a00 += v0.x * w0.x + v0.y * w0.z + v0.z * w1.x + v0.w * w1.z;
            a01 += v0.x * w0.y + v0.y * w0.w + v0.z * w1.y + v0.w * w1.w;
            a10 += v1.x * w0.x + v1.y * w0.z + v1.z * w1.x + v1.w * w1.z;
            a11 += v1.x * w0.y + v1.y * w0.w + v1.z * w1.y + v1.w * w1.w;
            a20 += v2.x * w0.x + v2.y * w0.z + v2.z * w1.x + v2.w * w1.z;
            a21 += v2.x * w0.y + v2.y * w0.w + v2.z * w1.y + v2.w * w1.w;
            a30 += v3.x * w0.x + v3.y * w0.z + v3.z * w1.x + v3.w * w1.z;
            a31 += v3.x * w0.y + v3.y * w0.w + v3.z * w1.y + v3.w * w1.w;
        }

        // reduce each accumulator across the 4 q-lanes (xor1 + xor2)
        a00 += __shfl_xor(a00, 1, 64);  a00 += __shfl_xor(a00, 2, 64);
        a01 += __shfl_xor(a01, 1, 64);  a01 += __shfl_xor(a01, 2, 64);
        a10 += __shfl_xor(a10, 1, 64);  a10 += __shfl_xor(a10, 2, 64);
        a11 += __shfl_xor(a11, 1, 64);  a11 += __shfl_xor(a11, 2, 64);
        a20 += __shfl_xor(a20, 1, 64);  a20 += __shfl_xor(a20, 2, 64);
        a21 += __shfl_xor(a21, 1, 64);  a21 += __shfl_xor(a21, 2, 64);
        a30 += __shfl_xor(a30, 1, 64);  a30 += __shfl_xor(a30, 2, 64);
        a31 += __shfl_xor(a31, 1, 64);  a31 += __shfl_xor(a31, 2, 64);

        if (q == 0) {
            const float b0 = bias[j * 2 + 0];
            const float b1 = bias[j * 2 + 1];
            float2 r0; r0.x = a00 + b0; r0.y = a01 + b1;
            float2 r1; r1.x = a10 + b0; r1.y = a11 + b1;
            float2 r2; r2.x = a20 + b0; r2.y = a21 + b1;
            float2 r3; r3.x = a30 + b0; r3.y = a31 + b1;
            *(float2*)(out + (size_t)p * 2)         = r0;
            *(float2*)(out + (size_t)(p + 192) * 2) = r1;
            *(float2*)(out + (size_t)(p + 384) * 2) = r2;
            *(float2*)(out + (size_t)(p + 576) * 2) = r3;
        }
    }
}

extern "C" void kernel_launch(void* const* d_in, const int* in_sizes, int n_in,
                              void* d_out, int out_size, void* d_ws, size_t ws_size,
                              hipStream_t stream) {
    const float* x    = (const float*)d_in[0];
    const float* W    = (const float*)d_in[1];
    const float* bias = (const float*)d_in[2];
    float* out        = (float*)d_out;

    const int B = in_sizes[0] / (13 * 256);       // 65536
    const int total_pairs = B * 12;               // 786432
    const int num_quads = total_pairs >> 6;       // 12288 (16 pairs/wave-batch x 4 batches)

    // 3072 blocks x 4 waves = 12288 waves -> exactly one quad per wave.
    const int blocks = (num_quads + 3) / 4;
    detok_kernel<<<blocks, 256, 0, stream>>>(x, W, bias, out, num_quads);
}